// Round 6
// baseline (87.936 us; speedup 1.0000x reference)
//
#include <hip/hip_runtime.h>
#include <hip/hip_fp16.h>

#define BB_ 8
#define VV_ 5023
#define FF_ 9976
#define HH_ 512

static constexpr long long OUT_UV   = 0;                                   // uvcoords_images (B,3,H,H)
static constexpr long long OUT_POS  = OUT_UV   + (long long)BB_*3*HH_*HH_; // pos_mask        (B,1,H,H)
static constexpr long long OUT_GRID = OUT_POS  + (long long)BB_*HH_*HH_;   // grid            (B,H,H,2)
static constexpr long long OUT_N    = OUT_GRID + (long long)BB_*HH_*HH_*2; // normals         (B,V,3)
static constexpr long long OUT_NIMG = OUT_N    + (long long)BB_*VV_*3;     // normal_images   (B,3,H,H)
static constexpr long long OUT_TN   = OUT_NIMG + (long long)BB_*3*HH_*HH_; // t_normals       (B,V,3)

__device__ inline float pack_h2(float a, float b) {
    union { float f; __half2 h; } u;
    u.h = __halves2half2(__float2half_rn(a), __float2half_rn(b));
    return u.f;
}
__device__ inline float2 unpack_h2(float w) {
    union { float f; __half2 h; } u; u.f = w;
    return __half22float2(u.h);
}

// ---------------------------------------------------------------------------
// K1: topology (count + scan + fill) in ONE single-block kernel, all LDS.
// Replaces memset + count-atomics + scan_k + fill_k.
// ---------------------------------------------------------------------------
__global__ __launch_bounds__(1024) void topo_k(const int* __restrict__ faces,
                                               int* __restrict__ offsets,
                                               int* __restrict__ list) {
    __shared__ int cnt[VV_];      // counters, then reused as fill cursors
    __shared__ int sums[1024];
    int tid = threadIdx.x;

    for (int v = tid; v < VV_; v += 1024) cnt[v] = 0;
    __syncthreads();
    for (int i = tid; i < FF_ * 3; i += 1024) atomicAdd(&cnt[faces[i]], 1);
    __syncthreads();

    // exclusive scan: 5 elements per thread + block scan over 1024 partials
    const int SEG = (VV_ + 1023) / 1024;   // 5
    int local[SEG];
    int s = 0;
    #pragma unroll
    for (int j = 0; j < SEG; ++j) {
        int v = tid * SEG + j;
        int c = (v < VV_) ? cnt[v] : 0;
        local[j] = s;
        s += c;
    }
    sums[tid] = s;
    __syncthreads();
    for (int st = 1; st < 1024; st <<= 1) {
        int add = (tid >= st) ? sums[tid - st] : 0;
        __syncthreads();
        sums[tid] += add;
        __syncthreads();
    }
    int base = (tid == 0) ? 0 : sums[tid - 1];
    __syncthreads();
    #pragma unroll
    for (int j = 0; j < SEG; ++j) {
        int v = tid * SEG + j;
        if (v < VV_) {
            int o = base + local[j];
            offsets[v] = o;
            cnt[v] = o;            // cursor
        }
    }
    if (tid == 0) offsets[VV_] = FF_ * 3;
    __syncthreads();

    for (int i = tid; i < FF_ * 3; i += 1024) {
        int v = faces[i];
        int slot = atomicAdd(&cnt[v], 1);
        list[slot] = i / 3;
    }
}

// ---------------------------------------------------------------------------
// K2: fused facenorm + gather. One thread per (b, mesh, v): recompute the
// cross product of each adjacent face from L1/L2-resident vertex slabs
// (identical arithmetic & summation order as before -> tnz bit-identical),
// normalize, write normals / t_normals outputs. No intermediate fnorm buffer.
// ---------------------------------------------------------------------------
__global__ __launch_bounds__(64) void vgather_k(const float* __restrict__ verts,
                                                const float* __restrict__ tverts,
                                                const int*   __restrict__ faces,
                                                const int*   __restrict__ offsets,
                                                const int*   __restrict__ list,
                                                float* __restrict__ outN,
                                                float* __restrict__ outTN) {
    int t = blockIdx.x * 64 + threadIdx.x;
    if (t >= BB_ * 2 * VV_) return;
    int bm = t / VV_;
    int v  = t - bm * VV_;
    int m  = bm & 1;
    int b  = bm >> 1;

    const float* vb = (m ? tverts : verts) + (long long)b * VV_ * 3;
    const float zoff = m ? 10.0f : 0.0f;

    int o0 = offsets[v], o1 = offsets[v + 1];
    float x = 0.f, y = 0.f, z = 0.f;
    for (int j = o0; j < o1; ++j) {
        int f = list[j];
        int i0 = faces[f*3+0], i1 = faces[f*3+1], i2 = faces[f*3+2];
        float v0x = vb[i0*3+0], v0y = vb[i0*3+1], v0z = vb[i0*3+2] + zoff;
        float v1x = vb[i1*3+0], v1y = vb[i1*3+1], v1z = vb[i1*3+2] + zoff;
        float v2x = vb[i2*3+0], v2y = vb[i2*3+1], v2z = vb[i2*3+2] + zoff;
        float ax = v1x - v0x, ay = v1y - v0y, az = v1z - v0z;
        float bx = v2x - v0x, by = v2y - v0y, bz = v2z - v0z;
        x += ay * bz - az * by;
        y += az * bx - ax * bz;
        z += ax * by - ay * bx;
    }
    float inv = 1.0f / fmaxf(sqrtf(x*x + y*y + z*z), 1e-6f);
    float* o = (m ? outTN : outN) + ((long long)b * VV_ + v) * 3;
    o[0] = x * inv; o[1] = y * inv; o[2] = z * inv;
}

// ---------------------------------------------------------------------------
// K3: ONE 64-B record per (b,f): everything raster needs in a single line.
//   q0: tnz0, tnz1, tnz2 (fp32 - hard-threshold path) , pack(uv8, ncz)
//   q1: uv0..7 as halves (pre-scaled)
//   q2: nax..ncy as halves
//   q3: pad (unwritten)
// ---------------------------------------------------------------------------
__global__ __launch_bounds__(128) void build_rec64(const int*   __restrict__ faces,
                                                   const float* __restrict__ uvc,
                                                   const float* __restrict__ outN,
                                                   const float* __restrict__ outTN,
                                                   float4* __restrict__ rec) {
    int t = blockIdx.x * 128 + threadIdx.x;
    if (t >= BB_ * FF_) return;
    int b = t / FF_;
    int f = t - b * FF_;
    int ia = faces[f*3+0], ib = faces[f*3+1], ic = faces[f*3+2];

    const float* nb = outN  + (long long)b * VV_ * 3;
    const float* tb = outTN + (long long)b * VV_ * 3;
    float nax = nb[ia*3+0], nay = nb[ia*3+1], naz = nb[ia*3+2];
    float nbx = nb[ib*3+0], nby = nb[ib*3+1], nbz = nb[ib*3+2];
    float ncx = nb[ic*3+0], ncy = nb[ic*3+1], ncz = nb[ic*3+2];
    float ta = tb[ia*3+2], tbv = tb[ib*3+2], tc = tb[ic*3+2];

    const float* u = uvc + (long long)f * 9;
    float r0 = u[0]*0.5f+0.5f, r1 = u[1]*0.5f+0.5f, r2 = u[2]*0.5f+0.5f;
    float r3 = u[3]*0.5f+0.5f, r4 = u[4]*0.5f+0.5f, r5 = u[5]*0.5f+0.5f;
    float r6 = u[6]*0.5f+0.5f, r7 = u[7]*0.5f+0.5f, r8 = u[8]*0.5f+0.5f;

    float4* o = rec + (long long)t * 4;
    o[0] = make_float4(ta, tbv, tc, pack_h2(r8, ncz));
    o[1] = make_float4(pack_h2(r0,r1), pack_h2(r2,r3), pack_h2(r4,r5), pack_h2(r6,r7));
    o[2] = make_float4(pack_h2(nax,nay), pack_h2(naz,nbx), pack_h2(nby,nbz), pack_h2(ncx,ncy));
}

// ---------------------------------------------------------------------------
// Per-pixel shade: 3 dwordx4 loads from ONE 64-B line; branch skips all
// gather traffic for miss pixels (~30%).
// ---------------------------------------------------------------------------
__device__ inline void shade(int pf, float w0, float w1, float w2,
                             const float4* __restrict__ rec,
                             float& uv0, float& uv1, float& uv2,
                             float& n0, float& n1, float& n2, float& pm) {
    uv0 = uv1 = uv2 = n0 = n1 = n2 = pm = 0.0f;
    if (pf < 0) return;
    const float4* R = rec + (long long)pf * 4;
    float4 q0 = R[0], q1 = R[1], q2 = R[2];

    float2 u8c = unpack_h2(q0.w);     // (uv8, ncz)
    float2 u01 = unpack_h2(q1.x), u23 = unpack_h2(q1.y);
    float2 u45 = unpack_h2(q1.z), u67 = unpack_h2(q1.w);
    float2 m01 = unpack_h2(q2.x), m23 = unpack_h2(q2.y);
    float2 m45 = unpack_h2(q2.z), m67 = unpack_h2(q2.w);

    uv0 = w0*u01.x + w1*u23.y + w2*u67.x;
    uv1 = w0*u01.y + w1*u45.x + w2*u67.y;
    uv2 = w0*u23.x + w1*u45.y + w2*u8c.x;
    n0  = w0*m01.x + w1*m23.y + w2*m67.x;
    n1  = w0*m01.y + w1*m45.x + w2*m67.y;
    n2  = w0*m23.x + w1*m45.y + w2*u8c.y;
    float tnz = w0*q0.x + w1*q0.y + w2*q0.z;   // fp32: hard threshold
    pm = (tnz < -0.05f) ? 1.0f : 0.0f;
}

// ---------------------------------------------------------------------------
// K4: raster, 4 consecutive pixels per thread; fully vectorized streams.
// ---------------------------------------------------------------------------
__global__ __launch_bounds__(256) void raster5(const int4*   __restrict__ p2f4,
                                               const float4* __restrict__ bary4,
                                               const float4* __restrict__ rec,
                                               float* __restrict__ out) {
    int t = blockIdx.x * blockDim.x + threadIdx.x;
    const int NQ = BB_ * HH_ * HH_ / 4;
    if (t >= NQ) return;
    int pix0 = t << 2;
    int b    = pix0 >> 18;               // H*H = 2^18
    int yx0  = pix0 & (HH_*HH_ - 1);

    int4   pf = p2f4[t];
    float4 B0 = bary4[(long long)t*3+0];
    float4 B1 = bary4[(long long)t*3+1];
    float4 B2 = bary4[(long long)t*3+2];

    float uv0a, uv1a, uv2a, n0a, n1a, n2a, pma;
    float uv0b, uv1b, uv2b, n0b, n1b, n2b, pmb;
    float uv0c, uv1c, uv2c, n0c, n1c, n2c, pmc;
    float uv0d, uv1d, uv2d, n0d, n1d, n2d, pmd;

    shade(pf.x, B0.x, B0.y, B0.z, rec, uv0a, uv1a, uv2a, n0a, n1a, n2a, pma);
    shade(pf.y, B0.w, B1.x, B1.y, rec, uv0b, uv1b, uv2b, n0b, n1b, n2b, pmb);
    shade(pf.z, B1.z, B1.w, B2.x, rec, uv0c, uv1c, uv2c, n0c, n1c, n2c, pmc);
    shade(pf.w, B2.y, B2.z, B2.w, rec, uv0d, uv1d, uv2d, n0d, n1d, n2d, pmd);

    const long long HW = (long long)HH_ * HH_;
    *(float4*)(out + OUT_UV  + ((long long)(b*3+0))*HW + yx0) = make_float4(uv0a, uv0b, uv0c, uv0d);
    *(float4*)(out + OUT_UV  + ((long long)(b*3+1))*HW + yx0) = make_float4(uv1a, uv1b, uv1c, uv1d);
    *(float4*)(out + OUT_UV  + ((long long)(b*3+2))*HW + yx0) = make_float4(uv2a, uv2b, uv2c, uv2d);
    *(float4*)(out + OUT_POS + (long long)b*HW + yx0)         = make_float4(pma, pmb, pmc, pmd);
    float* gbase = out + OUT_GRID + ((long long)b*HW + yx0)*2;
    *(float4*)(gbase + 0) = make_float4(uv0a, uv1a, uv0b, uv1b);
    *(float4*)(gbase + 4) = make_float4(uv0c, uv1c, uv0d, uv1d);
    *(float4*)(out + OUT_NIMG + ((long long)(b*3+0))*HW + yx0) = make_float4(n0a, n0b, n0c, n0d);
    *(float4*)(out + OUT_NIMG + ((long long)(b*3+1))*HW + yx0) = make_float4(n1a, n1b, n1c, n1d);
    *(float4*)(out + OUT_NIMG + ((long long)(b*3+2))*HW + yx0) = make_float4(n2a, n2b, n2c, n2d);
}

extern "C" void kernel_launch(void* const* d_in, const int* in_sizes, int n_in,
                              void* d_out, int out_size, void* d_ws, size_t ws_size,
                              hipStream_t stream) {
    const float* vertices  = (const float*)d_in[0];
    const float* tvertices = (const float*)d_in[1];
    const float* face_uvc  = (const float*)d_in[3];
    const float* bary      = (const float*)d_in[4];
    const int*   faces     = (const int*)d_in[5];
    const int*   p2f       = (const int*)d_in[6];

    float* out = (float*)d_out;

    // ws layout (16B-aligned first): rec (B*F*64 B = 5.1 MB) | offsets | list
    float4* rec     = (float4*)d_ws;                         // B*F*4 float4
    int*    offsets = (int*)(rec + (size_t)BB_ * FF_ * 4);   // V+1
    int*    list    = offsets + VV_ + 1;                     // F*3

    topo_k<<<1, 1024, 0, stream>>>(faces, offsets, list);
    {
        int n = BB_ * 2 * VV_;
        vgather_k<<<(n + 63) / 64, 64, 0, stream>>>(vertices, tvertices, faces,
                                                    offsets, list, out + OUT_N, out + OUT_TN);
    }
    {
        int n = BB_ * FF_;
        build_rec64<<<(n + 127) / 128, 128, 0, stream>>>(faces, face_uvc,
                                                         out + OUT_N, out + OUT_TN, rec);
    }
    {
        int nq = BB_ * HH_ * HH_ / 4;
        raster5<<<(nq + 255) / 256, 256, 0, stream>>>((const int4*)p2f, (const float4*)bary,
                                                      rec, out);
    }
}

// Round 7
// 69.063 us; speedup vs baseline: 1.2733x; 1.2733x over previous
//
#include <hip/hip_runtime.h>
#include <hip/hip_fp16.h>

#define BB_ 8
#define VV_ 5023
#define FF_ 9976
#define HH_ 512
#define K_ADJ 32

static constexpr long long OUT_UV   = 0;                                   // uvcoords_images (B,3,H,H)
static constexpr long long OUT_POS  = OUT_UV   + (long long)BB_*3*HH_*HH_; // pos_mask        (B,1,H,H)
static constexpr long long OUT_GRID = OUT_POS  + (long long)BB_*HH_*HH_;   // grid            (B,H,H,2)
static constexpr long long OUT_N    = OUT_GRID + (long long)BB_*HH_*HH_*2; // normals         (B,V,3)
static constexpr long long OUT_NIMG = OUT_N    + (long long)BB_*VV_*3;     // normal_images   (B,3,H,H)
static constexpr long long OUT_TN   = OUT_NIMG + (long long)BB_*3*HH_*HH_; // t_normals       (B,V,3)

typedef float __attribute__((ext_vector_type(4))) f4;
typedef int   __attribute__((ext_vector_type(4))) i4;

__device__ inline float pack_h2(float a, float b) {
    union { float f; __half2 h; } u;
    u.h = __halves2half2(__float2half_rn(a), __float2half_rn(b));
    return u.f;
}
__device__ inline float2 unpack_h2(float w) {
    union { float f; __half2 h; } u; u.f = w;
    return __half22float2(u.h);
}

// ---------------------------------------------------------------------------
// K1: one face normal per (b, mesh, f); bm==0 lanes also build the fixed-
// capacity adjacency table (int atomics; K=32 >> max degree for F=9976,
// V=5023 random faces). All three reference scatter-adds equal
// cross(v1-v0, v2-v0); z+10 applied before differencing (matches ref bits).
// ---------------------------------------------------------------------------
__global__ __launch_bounds__(256) void facenorm_k(const float* __restrict__ verts,
                                                  const float* __restrict__ tverts,
                                                  const int*   __restrict__ faces,
                                                  float* __restrict__ fnorm,
                                                  int*   __restrict__ cnt,
                                                  int*   __restrict__ adj) {
    int t = blockIdx.x * blockDim.x + threadIdx.x;
    if (t >= BB_ * 2 * FF_) return;
    int bm = t / FF_;
    int f  = t - bm * FF_;
    int m  = bm & 1;
    int b  = bm >> 1;

    const float* vb = (m ? tverts : verts) + (long long)b * VV_ * 3;
    const float zoff = m ? 10.0f : 0.0f;

    int i0 = faces[f*3+0], i1 = faces[f*3+1], i2 = faces[f*3+2];
    float v0x = vb[i0*3+0], v0y = vb[i0*3+1], v0z = vb[i0*3+2] + zoff;
    float v1x = vb[i1*3+0], v1y = vb[i1*3+1], v1z = vb[i1*3+2] + zoff;
    float v2x = vb[i2*3+0], v2y = vb[i2*3+1], v2z = vb[i2*3+2] + zoff;
    float ax = v1x - v0x, ay = v1y - v0y, az = v1z - v0z;
    float bx = v2x - v0x, by = v2y - v0y, bz = v2z - v0z;
    fnorm[(long long)t*3+0] = ay * bz - az * by;
    fnorm[(long long)t*3+1] = az * bx - ax * bz;
    fnorm[(long long)t*3+2] = ax * by - ay * bx;

    if (bm == 0) {
        int s0 = atomicAdd(&cnt[i0], 1); if (s0 < K_ADJ) adj[i0*K_ADJ + s0] = f;
        int s1 = atomicAdd(&cnt[i1], 1); if (s1 < K_ADJ) adj[i1*K_ADJ + s1] = f;
        int s2 = atomicAdd(&cnt[i2], 1); if (s2 < K_ADJ) adj[i2*K_ADJ + s2] = f;
    }
}

// ---------------------------------------------------------------------------
// K2: gather per (bm, v): sum adjacent face normals from the L2-resident
// fnorm buffer (1.9 MB), normalize, write normals / t_normals outputs.
// ---------------------------------------------------------------------------
__global__ __launch_bounds__(256) void gather_k(const int* __restrict__ cnt,
                                                const int* __restrict__ adj,
                                                const float* __restrict__ fnorm,
                                                float* __restrict__ outN,
                                                float* __restrict__ outTN) {
    int t = blockIdx.x * blockDim.x + threadIdx.x;
    if (t >= BB_ * 2 * VV_) return;
    int bm = t / VV_;
    int v  = t - bm * VV_;
    int deg = min(cnt[v], K_ADJ);
    const float* fb = fnorm + (long long)bm * FF_ * 3;
    float x = 0.f, y = 0.f, z = 0.f;
    for (int j = 0; j < deg; ++j) {
        int f = adj[v*K_ADJ + j];
        x += fb[f*3+0];
        y += fb[f*3+1];
        z += fb[f*3+2];
    }
    float inv = 1.0f / fmaxf(sqrtf(x*x + y*y + z*z), 1e-6f);
    float* o = ((bm & 1) ? outTN : outN) + ((long long)(bm >> 1) * VV_ + v) * 3;
    o[0] = x * inv; o[1] = y * inv; o[2] = z * inv;
}

// ---------------------------------------------------------------------------
// K3: ONE 64-B record per (b,f): everything raster needs in a single line.
//   q0: tnz0, tnz1, tnz2 (fp32 - hard-threshold path), pack(uv8, ncz)
//   q1: uv0..7 halves (pre-scaled);  q2: nax..ncy halves;  q3: pad.
// ---------------------------------------------------------------------------
__global__ __launch_bounds__(256) void build_rec64(const int*   __restrict__ faces,
                                                   const float* __restrict__ uvc,
                                                   const float* __restrict__ outN,
                                                   const float* __restrict__ outTN,
                                                   float4* __restrict__ rec) {
    int t = blockIdx.x * blockDim.x + threadIdx.x;
    if (t >= BB_ * FF_) return;
    int b = t / FF_;
    int f = t - b * FF_;
    int ia = faces[f*3+0], ib = faces[f*3+1], ic = faces[f*3+2];

    const float* nb = outN  + (long long)b * VV_ * 3;
    const float* tb = outTN + (long long)b * VV_ * 3;
    float nax = nb[ia*3+0], nay = nb[ia*3+1], naz = nb[ia*3+2];
    float nbx = nb[ib*3+0], nby = nb[ib*3+1], nbz = nb[ib*3+2];
    float ncx = nb[ic*3+0], ncy = nb[ic*3+1], ncz = nb[ic*3+2];
    float ta = tb[ia*3+2], tbv = tb[ib*3+2], tc = tb[ic*3+2];

    const float* u = uvc + (long long)f * 9;
    float r0 = u[0]*0.5f+0.5f, r1 = u[1]*0.5f+0.5f, r2 = u[2]*0.5f+0.5f;
    float r3 = u[3]*0.5f+0.5f, r4 = u[4]*0.5f+0.5f, r5 = u[5]*0.5f+0.5f;
    float r6 = u[6]*0.5f+0.5f, r7 = u[7]*0.5f+0.5f, r8 = u[8]*0.5f+0.5f;

    float4* o = rec + (long long)t * 4;
    o[0] = make_float4(ta, tbv, tc, pack_h2(r8, ncz));
    o[1] = make_float4(pack_h2(r0,r1), pack_h2(r2,r3), pack_h2(r4,r5), pack_h2(r6,r7));
    o[2] = make_float4(pack_h2(nax,nay), pack_h2(naz,nbx), pack_h2(nby,nbz), pack_h2(ncx,ncy));
}

// ---------------------------------------------------------------------------
// Per-pixel shade: 3 dwordx4 loads from ONE 64-B line; miss pixels (~30%)
// issue zero gather traffic.
// ---------------------------------------------------------------------------
__device__ inline void shade(int pf, float w0, float w1, float w2,
                             const float4* __restrict__ rec,
                             float& uv0, float& uv1, float& uv2,
                             float& n0, float& n1, float& n2, float& pm) {
    uv0 = uv1 = uv2 = n0 = n1 = n2 = pm = 0.0f;
    if (pf < 0) return;
    const float4* R = rec + (long long)pf * 4;
    float4 q0 = R[0], q1 = R[1], q2 = R[2];

    float2 u8c = unpack_h2(q0.w);     // (uv8, ncz)
    float2 u01 = unpack_h2(q1.x), u23 = unpack_h2(q1.y);
    float2 u45 = unpack_h2(q1.z), u67 = unpack_h2(q1.w);
    float2 m01 = unpack_h2(q2.x), m23 = unpack_h2(q2.y);
    float2 m45 = unpack_h2(q2.z), m67 = unpack_h2(q2.w);

    uv0 = w0*u01.x + w1*u23.y + w2*u67.x;
    uv1 = w0*u01.y + w1*u45.x + w2*u67.y;
    uv2 = w0*u23.x + w1*u45.y + w2*u8c.x;
    n0  = w0*m01.x + w1*m23.y + w2*m67.x;
    n1  = w0*m01.y + w1*m45.x + w2*m67.y;
    n2  = w0*m23.x + w1*m45.y + w2*u8c.y;
    float tnz = w0*q0.x + w1*q0.y + w2*q0.z;   // fp32: hard threshold
    pm = (tnz < -0.05f) ? 1.0f : 0.0f;
}

// ---------------------------------------------------------------------------
// K4: raster, 4 consecutive pixels/thread. NT loads for read-once streams,
// NT stores for write-once outputs -> L2 reserved for the 5.1 MB rec table.
// ---------------------------------------------------------------------------
__global__ __launch_bounds__(256) void raster6(const i4* __restrict__ p2f4,
                                               const f4* __restrict__ bary4,
                                               const float4* __restrict__ rec,
                                               float* __restrict__ out) {
    int t = blockIdx.x * blockDim.x + threadIdx.x;
    const int NQ = BB_ * HH_ * HH_ / 4;
    if (t >= NQ) return;
    int pix0 = t << 2;
    int b    = pix0 >> 18;               // H*H = 2^18
    int yx0  = pix0 & (HH_*HH_ - 1);

    i4 pf = __builtin_nontemporal_load(p2f4 + t);
    f4 B0 = __builtin_nontemporal_load(bary4 + (long long)t*3 + 0);
    f4 B1 = __builtin_nontemporal_load(bary4 + (long long)t*3 + 1);
    f4 B2 = __builtin_nontemporal_load(bary4 + (long long)t*3 + 2);

    float uv0a, uv1a, uv2a, n0a, n1a, n2a, pma;
    float uv0b, uv1b, uv2b, n0b, n1b, n2b, pmb;
    float uv0c, uv1c, uv2c, n0c, n1c, n2c, pmc;
    float uv0d, uv1d, uv2d, n0d, n1d, n2d, pmd;

    shade(pf.x, B0.x, B0.y, B0.z, rec, uv0a, uv1a, uv2a, n0a, n1a, n2a, pma);
    shade(pf.y, B0.w, B1.x, B1.y, rec, uv0b, uv1b, uv2b, n0b, n1b, n2b, pmb);
    shade(pf.z, B1.z, B1.w, B2.x, rec, uv0c, uv1c, uv2c, n0c, n1c, n2c, pmc);
    shade(pf.w, B2.y, B2.z, B2.w, rec, uv0d, uv1d, uv2d, n0d, n1d, n2d, pmd);

    const long long HW = (long long)HH_ * HH_;
    f4 vuv0 = {uv0a, uv0b, uv0c, uv0d};
    f4 vuv1 = {uv1a, uv1b, uv1c, uv1d};
    f4 vuv2 = {uv2a, uv2b, uv2c, uv2d};
    f4 vpos = {pma,  pmb,  pmc,  pmd};
    f4 vg0  = {uv0a, uv1a, uv0b, uv1b};
    f4 vg1  = {uv0c, uv1c, uv0d, uv1d};
    f4 vn0  = {n0a, n0b, n0c, n0d};
    f4 vn1  = {n1a, n1b, n1c, n1d};
    f4 vn2  = {n2a, n2b, n2c, n2d};

    __builtin_nontemporal_store(vuv0, (f4*)(out + OUT_UV  + ((long long)(b*3+0))*HW + yx0));
    __builtin_nontemporal_store(vuv1, (f4*)(out + OUT_UV  + ((long long)(b*3+1))*HW + yx0));
    __builtin_nontemporal_store(vuv2, (f4*)(out + OUT_UV  + ((long long)(b*3+2))*HW + yx0));
    __builtin_nontemporal_store(vpos, (f4*)(out + OUT_POS + (long long)b*HW + yx0));
    float* gbase = out + OUT_GRID + ((long long)b*HW + yx0)*2;
    __builtin_nontemporal_store(vg0, (f4*)(gbase + 0));
    __builtin_nontemporal_store(vg1, (f4*)(gbase + 4));
    __builtin_nontemporal_store(vn0, (f4*)(out + OUT_NIMG + ((long long)(b*3+0))*HW + yx0));
    __builtin_nontemporal_store(vn1, (f4*)(out + OUT_NIMG + ((long long)(b*3+1))*HW + yx0));
    __builtin_nontemporal_store(vn2, (f4*)(out + OUT_NIMG + ((long long)(b*3+2))*HW + yx0));
}

extern "C" void kernel_launch(void* const* d_in, const int* in_sizes, int n_in,
                              void* d_out, int out_size, void* d_ws, size_t ws_size,
                              hipStream_t stream) {
    const float* vertices  = (const float*)d_in[0];
    const float* tvertices = (const float*)d_in[1];
    const float* face_uvc  = (const float*)d_in[3];
    const float* bary      = (const float*)d_in[4];
    const int*   faces     = (const int*)d_in[5];
    const int*   p2f       = (const int*)d_in[6];

    float* out = (float*)d_out;

    // ws layout (16B-aligned first): rec | fnorm | cnt | adj   (~7.7 MB)
    float4* rec   = (float4*)d_ws;                               // B*F*4 float4
    float*  fnorm = (float*)(rec + (size_t)BB_ * FF_ * 4);       // B*2*F*3
    int*    cnt   = (int*)(fnorm + (size_t)BB_ * 2 * FF_ * 3);   // V
    int*    adj   = cnt + VV_;                                   // V*K_ADJ

    hipMemsetAsync(cnt, 0, (size_t)VV_ * sizeof(int), stream);

    {
        int n = BB_ * 2 * FF_;
        facenorm_k<<<(n + 255) / 256, 256, 0, stream>>>(vertices, tvertices, faces,
                                                        fnorm, cnt, adj);
    }
    {
        int n = BB_ * 2 * VV_;
        gather_k<<<(n + 255) / 256, 256, 0, stream>>>(cnt, adj, fnorm,
                                                      out + OUT_N, out + OUT_TN);
    }
    {
        int n = BB_ * FF_;
        build_rec64<<<(n + 255) / 256, 256, 0, stream>>>(faces, face_uvc,
                                                         out + OUT_N, out + OUT_TN, rec);
    }
    {
        int nq = BB_ * HH_ * HH_ / 4;
        raster6<<<(nq + 255) / 256, 256, 0, stream>>>((const i4*)p2f, (const f4*)bary,
                                                      rec, out);
    }
}